// Round 5
// baseline (299.532 us; speedup 1.0000x reference)
//
#include <hip/hip_runtime.h>
#include <cmath>

// PSNR + 3D-SSIM, pred/gt (N=4, C=16->D, H=512, W=512) f32.
// R13 = R12's MFMA math with the serialization removed (R12: all pipes idle,
// 2 barriers/slice, serial ds_read phase, 200us).
//  - sd double-buffered (16 KB) -> ONE barrier per slice (16 total).
//    barrier(d) alone separates read(d-1) from write(d+1) (other buffer).
//  - Blur order swapped: W-GEMM first (A = staged rows, B = std-sigma
//    Gaussian table), H-GEMM second (A = pack-sigma table, B = packed T2).
//    Same host tables as R12 (A/B fragment symmetry); same C-layout px
//    mapping -> history/Ostack/epilogue copied verbatim (verified in R12).
//  - New [ch][r][c-contig] layout: frag reads perfectly bank-balanced
//    (uint4 idx 4*lo+hi -> 8 lanes/group), stage writes ~3-way (was ~13).
//  - Per slice: stage -> barrier -> {prefetch issue, 2 b128 frag reads,
//    3 MFMAs, pack, ost write} in one region; 12 waves/CU overlap.

#define NB 4
#define DD 16
#define HH 512
#define WW 512
#define SLICE (HH * WW)
#define VOL (DD * SLICE)
#define C1F 0.0001f
#define C2F 0.0009f
#define NTHR 256

typedef _Float16 h8 __attribute__((ext_vector_type(8)));
typedef float f4 __attribute__((ext_vector_type(4)));

__device__ inline f4 mfma16(uint4 a, uint4 b, f4 c) {
  return __builtin_amdgcn_mfma_f32_16x16x32_f16(
      __builtin_bit_cast(h8, a), __builtin_bit_cast(h8, b), c, 0, 0, 0);
}
__device__ inline unsigned pkh(float a, float b) {
  return __builtin_bit_cast(unsigned, __builtin_amdgcn_cvt_pkrtz(a, b));
}
__device__ inline int iclamp(int v, int lo, int hi) {
  return v < lo ? lo : (v > hi ? hi : v);
}

__device__ inline float block_sum256(float v) {
#pragma unroll
  for (int o = 32; o > 0; o >>= 1) v += __shfl_down(v, o, 64);
  __shared__ float r[4];
  if ((threadIdx.x & 63) == 0) r[threadIdx.x >> 6] = v;
  __syncthreads();
  float out = 0.f;
  if (threadIdx.x == 0) {
#pragma unroll
    for (int i = 0; i < 4; ++i) out += r[i];
  }
  __syncthreads();
  return out;
}

__global__ void zero_acc_k(float* acc) {
  if (threadIdx.x < 8) acc[threadIdx.x] = 0.f;
}

// sd: [buf2][ch4][r32][c32] f16, c contiguous. u32 idx = buf*2048 + ch*512
//     + r*16 + cp (cp = col-pair). rows 26..31 and cols 26..31 stay zero.
// ost: [ch4][px256][d16] f16, d-quad at Q^(2*(px>>6&1)) (as R12).
__global__ __launch_bounds__(NTHR, 3) void fused_k(
    const float* __restrict__ pred, const float* __restrict__ gt,
    float* __restrict__ acc, const uint4* __restrict__ tabs) {
  __shared__ _Float16 sd[2 * 4 * 32 * 32];   // 16384 B
  __shared__ _Float16 ost[4 * 256 * 16];     // 32768 B
  __shared__ uint4 zzq;                      // zeros for K-pad reads

  int b = blockIdx.x;
  int tile = b & 1023;               // 32 h-tiles x 32 w-tiles
  int n = b >> 10;
  int th0 = (tile >> 5) * 16;
  int tw0 = (tile & 31) * 16;
  int t = threadIdx.x;
  int lane = t & 63, wv = t >> 6;
  int lo = lane & 15, hi = lane >> 4;

  // constant fragments (identical tables to R12)
  uint4 gstd = tabs[lane];        // std-sigma Gaussian: B of W-GEMM
  uint4 gpck = tabs[64 + lane];   // pack-sigma Gaussian: A of H-GEMM
  uint4 wlf = tabs[128 + lane];   // WL: A of D-GEMM

  // zero-init sd (both buffers; pads must stay 0) + zzq
  unsigned* sdw = (unsigned*)sd;
#pragma unroll
  for (int i = 0; i < 16; ++i) sdw[t + i * 256] = 0;
  if (t == 0) zzq = make_uint4(0, 0, 0, 0);

  // ---- stage metadata, slot 0: item t = (row r, col-pair cp), cp-minor
  int r0 = t / 13, cp0 = t - r0 * 13;
  int gy0 = iclamp(th0 + r0 - 5, 0, HH - 1);
  int ga0 = gy0 * WW + iclamp(tw0 + 2 * cp0 - 5, 0, WW - 1);
  int gb0 = gy0 * WW + iclamp(tw0 + 2 * cp0 - 4, 0, WW - 1);
  int w0 = r0 * 16 + cp0;
  bool orow0 = (r0 >= 5) && (r0 <= 20);
  float o0a = (orow0 && cp0 >= 3 && cp0 <= 10) ? 1.f : 0.f;  // col 2cp
  float o0b = (orow0 && cp0 >= 2 && cp0 <= 9) ? 1.f : 0.f;   // col 2cp+1
  // slot 1 (items 256..337 -> threads 174..255)
  int i1 = t + 82;
  bool has2 = (i1 >= NTHR);
  int r1 = i1 / 13, cp1 = i1 - r1 * 13;
  int gy1 = iclamp(th0 + r1 - 5, 0, HH - 1);
  int ga1 = gy1 * WW + iclamp(tw0 + 2 * cp1 - 5, 0, WW - 1);
  int gb1 = gy1 * WW + iclamp(tw0 + 2 * cp1 - 4, 0, WW - 1);
  int w1 = r1 * 16 + cp1;
  bool orow1 = (r1 >= 5) && (r1 <= 20);
  float o1a = (orow1 && cp1 >= 3 && cp1 <= 10) ? 1.f : 0.f;
  float o1b = (orow1 && cp1 >= 2 && cp1 <= 9) ? 1.f : 0.f;

  const float* pb = pred + (size_t)n * VOL;
  const float* qb = gt + (size_t)n * VOL;

  // prefetch slice 0
  float p0a = pb[ga0], p0b = pb[gb0], q0a = qb[ga0], q0b = qb[gb0];
  float p1a = 0.f, p1b = 0.f, q1a = 0.f, q1b = 0.f;
  if (has2) { p1a = pb[ga1]; p1b = pb[gb1]; q1a = qb[ga1]; q1b = qb[gb1]; }

  // O addressing (u64 units): ch*1024 + px*4 + Q', px = 64hi+16reg+lo
  int owb = wv * 1024 + (64 * hi + lo) * 4;
  int qx = 2 * (hi & 1);             // Q' = (d>>2) ^ qx
  int fb = wv * 128 + lo * 4 + hi;   // uint4 frag base (rows lo); +64: lo+16
  const uint4* sdq = (const uint4*)sd;
  f4 z4 = {0.f, 0.f, 0.f, 0.f};

  float psnr = 0.f;
  float oe0, oe1, oe2, oe3;                         // even-d O values
  unsigned pA0, pA1, pA2, pA3, pB0, pB1, pB2, pB3;  // packed d-pairs
  oe0 = oe1 = oe2 = oe3 = 0.f;
  pA0 = pA1 = pA2 = pA3 = pB0 = pB1 = pB2 = pB3 = 0u;

  __syncthreads();   // zero-init visible

#pragma unroll 1
  for (int d = 0; d < DD; ++d) {
    unsigned* sb = sdw + (d & 1) * 2048;
    // ---- stage slice d (4 b32 writes per item: col-pair packed)
    {
      float SA = p0a + q0a, DA = p0a - q0a;   // col 2cp
      float SB = p0b + q0b, DB = p0b - q0b;   // col 2cp+1
      float dA = DA * DA, dB = DB * DB;
      psnr = fmaf(o0a, dA, psnr);
      psnr = fmaf(o0b, dB, psnr);
      sb[w0]        = pkh(SA, SB);
      sb[512 + w0]  = pkh(DA, DB);
      sb[1024 + w0] = pkh(SA * SA, SB * SB);
      sb[1536 + w0] = pkh(dA, dB);
    }
    if (has2) {
      float SA = p1a + q1a, DA = p1a - q1a;
      float SB = p1b + q1b, DB = p1b - q1b;
      float dA = DA * DA, dB = DB * DB;
      psnr = fmaf(o1a, dA, psnr);
      psnr = fmaf(o1b, dB, psnr);
      sb[w1]        = pkh(SA, SB);
      sb[512 + w1]  = pkh(DA, DB);
      sb[1024 + w1] = pkh(SA * SA, SB * SB);
      sb[1536 + w1] = pkh(dA, dB);
    }
    __syncthreads();   // ONLY barrier per slice: stage(d) visible; also
                       // separates read(d-1) from write(d+1) (same buffer)

    // ---- prefetch slice d+1 (longest latency: issue first)
    if (d < DD - 1) {
      const float* P = pb + (size_t)(d + 1) * SLICE;
      const float* Q = qb + (size_t)(d + 1) * SLICE;
      p0a = P[ga0]; p0b = P[gb0]; q0a = Q[ga0]; q0b = Q[gb0];
      if (has2) { p1a = P[ga1]; p1b = P[gb1]; q1a = Q[ga1]; q1b = Q[gb1]; }
    }

    // ---- frag reads (bank-balanced: idx = 4*lo+hi -> 8 lanes/group)
    uint4 fa0 = sdq[(d & 1) * 512 + fb];        // rows lo
    uint4 fa1 = sdq[(d & 1) * 512 + fb + 64];   // rows lo+16 (26..31 zero)

    // ---- W-GEMM (A=data, B=std table), pack, H-GEMM (A=pack table, B=T2)
    f4 t0 = mfma16(fa0, gstd, z4);   // T2[r=4hi+reg][w=lo], r 0..15
    f4 t1 = mfma16(fa1, gstd, z4);   // r 16..31
    uint4 ta = make_uint4(pkh(t0.x, t0.y), pkh(t0.z, t0.w),
                          pkh(t1.x, t1.y), pkh(t1.z, t1.w));
    f4 o = mfma16(gpck, ta, z4);     // Out px(row 4hi+reg, col lo)

    // ---- pack O across 4 slices -> one ds_write_b64 per reg per quad
    if ((d & 1) == 0) {
      oe0 = o.x; oe1 = o.y; oe2 = o.z; oe3 = o.w;
    } else if ((d & 2) == 0) {
      pA0 = pkh(oe0, o.x); pA1 = pkh(oe1, o.y);
      pA2 = pkh(oe2, o.z); pA3 = pkh(oe3, o.w);
    } else {
      pB0 = pkh(oe0, o.x); pB1 = pkh(oe1, o.y);
      pB2 = pkh(oe2, o.z); pB3 = pkh(oe3, o.w);
      int Qp = (d >> 2) ^ qx;
      uint2* op = (uint2*)ost;
      op[owb + Qp]       = make_uint2(pA0, pB0);
      op[owb + 64 + Qp]  = make_uint2(pA1, pB1);
      op[owb + 128 + Qp] = make_uint2(pA2, pB2);
      op[owb + 192 + Qp] = make_uint2(pA3, pB3);
    }
  }
  __syncthreads();   // Ostack complete (cross-wave)

  // ---- epilogue: D-GEMM (A=WL) + SSIM; waves own px-quadrants (as R12)
  const uint4* oq = (const uint4*)ost;
  int bnt = wv & 1;
  int blk = (hi < 2) ? (hi ^ bnt) : 0;
  bool real = (hi < 2);
  float ssum = 0.f;
#pragma unroll
  for (int q = 0; q < 4; ++q) {
    int nt = 4 * wv + q;
    int bidx = (16 * nt + lo) * 2 + blk;
    const uint4* bp0 = real ? &oq[bidx] : &zzq;
    const uint4* bp1 = real ? &oq[512 + bidx] : &zzq;
    const uint4* bp2 = real ? &oq[1024 + bidx] : &zzq;
    const uint4* bp3 = real ? &oq[1536 + bidx] : &zzq;
    f4 cS = mfma16(wlf, *bp0, z4);
    f4 cD = mfma16(wlf, *bp1, z4);
    f4 cS2 = mfma16(wlf, *bp2, z4);
    f4 cD2 = mfma16(wlf, *bp3, z4);
#pragma unroll
    for (int r = 0; r < 4; ++r) {
      float Sb = cS[r], Db = cD[r], B1 = cS2[r], B2 = cD2[r];
      float SS = Sb * Sb, DDm = Db * Db;
      float m12_2 = (SS - DDm) * 0.5f;
      float msq = (SS + DDm) * 0.5f;
      float Epq = (B1 - B2) * 0.25f;
      float Esum = (B1 + B2) * 0.5f;
      float sig12_2 = 2.f * Epq - m12_2;
      float svar = Esum - msq;
      float num = (m12_2 + C1F) * (sig12_2 + C2F);
      float den = (msq + C1F) * (svar + C2F);
      ssum += num / den;
    }
  }
  float bs = block_sum256(ssum);
  if (t == 0) atomicAdd(&acc[4 + n], bs);
  float bp = block_sum256(psnr);
  if (t == 0) atomicAdd(&acc[n], bp);
}

__global__ void final_k(const float* __restrict__ acc, float* __restrict__ out) {
  if (threadIdx.x == 0 && blockIdx.x == 0) {
    double psnr = 0.0, ssim = 0.0;
    for (int n = 0; n < NB; ++n) {
      double mse = (double)acc[n] / (double)VOL;
      psnr += 10.0 * log10(1.0 / mse);
      ssim += (double)acc[4 + n] / (double)VOL;
    }
    out[0] = (float)psnr;
    out[1] = (float)ssim;
    out[2] = (float)NB;
  }
}

// host f32 -> f16 (RNE)
static unsigned short f2h(float f) {
  union { float f; unsigned u; } v; v.f = f;
  unsigned u = v.u;
  unsigned s = (u >> 16) & 0x8000u;
  int e = (int)((u >> 23) & 0xff) - 127 + 15;
  unsigned m = u & 0x7fffffu;
  if (e <= 0) return (unsigned short)s;
  if (e >= 31) return (unsigned short)(s | 0x7c00u);
  unsigned h = ((unsigned)e << 10) | (m >> 13);
  unsigned rem = m & 0x1fffu;
  if (rem > 0x1000u || (rem == 0x1000u && (h & 1u))) h++;
  return (unsigned short)(s | h);
}
static float h2f(unsigned short h) {
  unsigned se = (h >> 10) & 0x1f, m = h & 0x3ffu, s = ((unsigned)h & 0x8000u) << 16;
  union { unsigned u; float f; } v;
  if (se == 0) { v.u = s; return v.f; }
  v.u = s | ((se - 15 + 127) << 23) | (m << 13);
  return v.f;
}

static unsigned s_tabs[192 * 4];   // 3 KB: std-sigma | pack-sigma | WL
static bool s_init = false;

extern "C" void kernel_launch(void* const* d_in, const int* in_sizes, int n_in,
                              void* d_out, int out_size, void* d_ws, size_t ws_size,
                              hipStream_t stream) {
  const float* pred = (const float*)d_in[0];
  const float* gt = (const float*)d_in[1];
  float* acc = (float*)d_ws;    // 8 floats @ +0; tables @ +64

  if (!s_init) {
    double tt[11], s = 0.0;
    for (int i = 0; i < 11; ++i) {
      double x = i - 5;
      tt[i] = exp(-(x * x) / 4.5);
      s += tt[i];
    }
    float g[11];
    for (int i = 0; i < 11; ++i) g[i] = (float)(tt[i] / s);
    unsigned short hg[11];
    for (int i = 0; i < 11; ++i) hg[i] = f2h(g[i]);
    for (int pass = 0; pass < 3; ++pass) {
      double sum = 0.0;
      for (int i = 0; i < 11; ++i) sum += (double)h2f(hg[i]);
      hg[5] = f2h((float)((double)h2f(hg[5]) + (1.0 - sum)));
    }
    float wl[DD][DD];
    for (int o = 0; o < DD; ++o)
      for (int d = 0; d < DD; ++d) {
        float w = 0.f;
        for (int k = 0; k < 11; ++k) {
          int j = o + k - 5;
          j = j < 0 ? 0 : (j > 15 ? 15 : j);
          if (j == d) w += g[k];
        }
        wl[d][o] = w;
      }
    unsigned short wlh[DD][DD];
    for (int o = 0; o < DD; ++o) {
      int dmx = 0;
      for (int d = 0; d < DD; ++d) {
        wlh[o][d] = f2h(wl[d][o]);
        if (wl[d][o] > wl[dmx][o]) dmx = d;
      }
      for (int pass = 0; pass < 3; ++pass) {
        double sum = 0.0;
        for (int d = 0; d < DD; ++d) sum += (double)h2f(wlh[o][d]);
        wlh[o][dmx] = f2h((float)((double)h2f(wlh[o][dmx]) + (1.0 - sum)));
      }
    }
    for (int l = 0; l < 64; ++l) {
      int lo = l & 15, hi = l >> 4;
      unsigned short v[8];
      // std-sigma: slot(hi,i) -> k = 8hi+i ; value g[k - lo]
      for (int i = 0; i < 8; ++i) {
        int idx = 8 * hi + i - lo;
        v[i] = (idx >= 0 && idx <= 10) ? hg[idx] : 0;
      }
      for (int k = 0; k < 4; ++k)
        s_tabs[l * 4 + k] = (unsigned)v[2 * k] | ((unsigned)v[2 * k + 1] << 16);
      // pack-sigma: slot(hi,i) -> k = 4hi+(i&3)+16(i>>2) ; value g[k - lo]
      for (int i = 0; i < 8; ++i) {
        int c = 4 * hi + (i & 3) + 16 * (i >> 2);
        int idx = c - lo;
        v[i] = (idx >= 0 && idx <= 10) ? hg[idx] : 0;
      }
      for (int k = 0; k < 4; ++k)
        s_tabs[(64 + l) * 4 + k] = (unsigned)v[2 * k] | ((unsigned)v[2 * k + 1] << 16);
      // WL: A[m=dout=lo][k=d=8hi+i]; zero for hi>=2 (K pad)
      for (int i = 0; i < 8; ++i)
        v[i] = (hi < 2) ? wlh[lo][8 * hi + i] : 0;
      for (int k = 0; k < 4; ++k)
        s_tabs[(128 + l) * 4 + k] = (unsigned)v[2 * k] | ((unsigned)v[2 * k + 1] << 16);
    }
    s_init = true;
  }

  hipMemcpyAsync((char*)d_ws + 64, s_tabs, sizeof(s_tabs),
                 hipMemcpyHostToDevice, stream);
  zero_acc_k<<<1, 64, 0, stream>>>(acc);
  fused_k<<<NB * 1024, NTHR, 0, stream>>>(pred, gt, acc,
                                          (const uint4*)((char*)d_ws + 64));
  final_k<<<1, 1, 0, stream>>>(acc, (float*)d_out);
}